// Round 4
// baseline (798.002 us; speedup 1.0000x reference)
//
#include <hip/hip_runtime.h>
#include <cstdint>

// Problem constants (fixed by setup_inputs): B=8, n=m=2048, iters=20.
#define BB 8
#define NN 2048
#define MM 2048
#define ITERS 20
#define BM (BB * MM)
#define BN (BB * NN)
#define LATE 6    // its [0,LATE) wide 1-wave/point kernel; rest in-block

typedef unsigned long long u64;
typedef unsigned short u16;

// r16 machine (223 us, absmax 0) + r4 late phase = one workgroup per batch:
//  - r1-r3 lesson: cross-workgroup barrier on this part costs a FIXED
//    ~32 us/round regardless of topology (1023 vs 31 pollers), poll op
//    (load vs RMW), sleep vs busy, fence placement. Grid barriers are a
//    dead end here. But batches are independent and each batch's late
//    state is private -> run late phase as 8 blocks (one per batch,
//    1024 thr = 16 waves, one CU each) iterating in-kernel with plain
//    __syncthreads() only. No cross-block sync AT ALL.
//  - per iteration: fold + status strided over 1024 threads; actives
//    compacted to an LDS list; then 1 WAVE PER ACTIVE POINT (wide shape)
//    runs the unchanged try_cert/scan_bid. __threadfence() once per
//    iteration invalidates the CU-shared L1 so plain reads observe the
//    previous iteration's atomicMax results (all traffic same-CU).
//  - atomicMax is order-free => nondeterministic active order cannot
//    change results; all math/key/parity logic byte-identical => absmax 0.
//  - final output pass folded into the same kernel (dispatches 22 -> 8).
//
// Workspace (bytes):
//   p2w    float4[2][BM]  xyz2 + price in .w   off 0        524288
//   pbuf   u64[2][BM]     tagged bid keys      off 524288   262144
//   assign int[2][BN]     point -> object      off 786432   131072
//   bidt   int[BN]        last bid target      off 917504    65536
//   bound  f32[BN]        cert bounds          off 983040    65536
//   cand   u16[BN*64]     t1|t2<<5|t3<<10      off 1048576 2097152
// total 3145728 (< proven-available 8978432).
//
// Bid key: (tag << 43) | (float_bits(incr) << 11) | (2047 - i)
//   tag = it+1 (0 = empty); fresh tags dominate stale under atomicMax so
//   pbuf is never reset. incr > 0 => float bit order == value order;
//   (2047-i) = min-index tie-break (reference min-winner semantics).
// Rotation (kernel it): p2w_old=p2w[it&1], p2w_new=p2w[(it+1)&1];
//   pb_read=pbuf[(it+1)&1], pb_write=pbuf[it&1]; assign likewise.

__global__ __launch_bounds__(256) void pack_kernel(
    const float* __restrict__ xyz2, float4* __restrict__ p2w,
    u64* __restrict__ pbuf) {
  int idx = blockIdx.x * 256 + threadIdx.x;  // [0, BM)
  p2w[idx] = make_float4(xyz2[idx * 3], xyz2[idx * 3 + 1],
                         xyz2[idx * 3 + 2], 0.f);
  pbuf[idx] = 0ULL;
  pbuf[BM + idx] = 0ULL;
}

// ---------- shared device helpers (inlined) ----------
__device__ __forceinline__ void post_bid(u64* __restrict__ pb_write,
                                         int* __restrict__ bidt,
                                         int b, int gi, int i, int j1,
                                         float v1, float v2, float eps,
                                         int it, int lane) {
  if (lane == 0) {
    float incr = (v1 - v2) + eps;        // top1 - top2 + eps
    u64 key = ((u64)(unsigned)(it + 1) << 43) |
              ((u64)__float_as_uint(incr) << 11) |
              (u64)(unsigned)(2047 - i);
    atomicMax(&pb_write[b * MM + j1], key);
    bidt[gi] = j1;
  }
}

// One exact candidate eval with one-behind price fold (reference ops).
__device__ __forceinline__ float eval_cand(
    const float4* __restrict__ pold, const u64* __restrict__ keys,
    float x1, float y1, float z1, int j, int it) {
  float4 q = pold[j];
  u64 k = keys[j];
  float pr = q.w;
  if ((int)(k >> 43) == it)
    pr = pr + __uint_as_float((unsigned)(k >> 11));      // reference add
  float dx = x1 - q.x, dy = y1 - q.y, dz = z1 - q.z;
  float c = dx * dx;
  c = c + dy * dy;                       // contract(off): matches numpy
  c = c + dz * dz;
  return -c - pr;                        // -cost - price, reference order
}

// Cert attempt for point (gi,i). Returns true if certified (bid posted).
__device__ __forceinline__ bool try_cert(
    const float4* __restrict__ pold, const u64* __restrict__ keys,
    const u16* __restrict__ cand, const float* __restrict__ bound,
    u64* __restrict__ pb_write, int* __restrict__ bidt,
    float x1, float y1, float z1, int b, int gi, int i, int it,
    float eps, int lane) {
  const float bnd = bound[gi];
  const unsigned cw = cand[((size_t)gi << 6) + lane];
  const int ja = (((int)cw & 31) << 6) + lane;
  const int jb = ((((int)cw >> 5) & 31) << 6) + lane;
  const int jc = ((((int)cw >> 10) & 31) << 6) + lane;
  float va = eval_cand(pold, keys, x1, y1, z1, ja, it);
  float vb = eval_cand(pold, keys, x1, y1, z1, jb, it);
  float vc = eval_cand(pold, keys, x1, y1, z1, jc, it);
  // within-lane top-2 of 3, exact (value, then min-index) ordering
  bool oab = (vb > va) || (vb == va && jb < ja);
  float h1 = oab ? vb : va;  int hj = oab ? jb : ja;
  float l1 = oab ? va : vb;  int lj = oab ? ja : jb;
  bool oc1 = (vc > h1) || (vc == h1 && jc < hj);
  bool oc2 = (vc > l1) || (vc == l1 && jc < lj);
  float v1 = oc1 ? vc : h1;
  int j1 = oc1 ? jc : hj;
  float v2 = oc1 ? h1 : (oc2 ? vc : l1);
  for (int o = 1; o < 64; o <<= 1) {
    float ov1 = __shfl_xor(v1, o, 64);
    float ov2 = __shfl_xor(v2, o, 64);
    int oj1 = __shfl_xor(j1, o, 64);
    bool w2 = (ov1 > v1) || (ov1 == v1 && oj1 < j1);
    float loser = w2 ? v1 : ov1;
    v1 = w2 ? ov1 : v1;
    j1 = w2 ? oj1 : j1;
    v2 = fmaxf(fmaxf(v2, ov2), loser);
  }
  if (v2 > bnd) {
    post_bid(pb_write, bidt, b, gi, i, j1, v1, v2, eps, it, lane);
    return true;
  }
  return false;
}

// Full scan (fold if it>0) + top-3/lane refresh + bid. Exact as r15's.
__device__ __forceinline__ void scan_bid(
    const float4* __restrict__ pold, const u64* __restrict__ keys,
    u16* __restrict__ cand, float* __restrict__ bound,
    u64* __restrict__ pb_write, int* __restrict__ bidt,
    float x1, float y1, float z1, int b, int gi, int i, int it,
    float eps, int lane) {
  const float NEG_INF = __int_as_float(0xff800000);
  float v1 = NEG_INF, v2 = NEG_INF, v3 = NEG_INF, b4 = NEG_INF;
  int t1 = 0, t2 = 0, t3 = 0;

  if (it == 0) {
#pragma unroll 4
    for (int t = 0; t < MM / 64; ++t) {
      int j = (t << 6) + lane;
      float4 q = pold[j];                // xyz + price, one 16B load
      float dx = x1 - q.x;
      float dy = y1 - q.y;
      float dz = z1 - q.z;
      float c = dx * dx;
      c = c + dy * dy;                   // contract(off): matches numpy
      c = c + dz * dz;
      float v = -c - q.w;                // -cost - price, reference order
      bool c1 = v > v1;
      bool c2 = v > v2;
      bool c3 = v > v3;
      b4 = fmaxf(b4, (c1 | c2 | c3) ? v3 : v);
      v3 = (c1 | c2) ? v2 : (c3 ? v : v3);
      t3 = (c1 | c2) ? t2 : (c3 ? t : t3);
      v2 = c1 ? v1 : (c2 ? v : v2);
      t2 = c1 ? t1 : (c2 ? t : t2);
      v1 = c1 ? v : v1;
      t1 = c1 ? t : t1;
    }
  } else {
#pragma unroll 4
    for (int t = 0; t < MM / 64; ++t) {
      int j = (t << 6) + lane;
      float4 q = pold[j];
      float pr = q.w;
      u64 k = keys[j];
      if ((int)(k >> 43) == it)
        pr = pr + __uint_as_float((unsigned)(k >> 11));   // reference add
      float dx = x1 - q.x;
      float dy = y1 - q.y;
      float dz = z1 - q.z;
      float c = dx * dx;
      c = c + dy * dy;
      c = c + dz * dz;
      float v = -c - pr;
      bool c1 = v > v1;
      bool c2 = v > v2;
      bool c3 = v > v3;
      b4 = fmaxf(b4, (c1 | c2 | c3) ? v3 : v);
      v3 = (c1 | c2) ? v2 : (c3 ? v : v3);
      t3 = (c1 | c2) ? t2 : (c3 ? t : t3);
      v2 = c1 ? v1 : (c2 ? v : v2);
      t2 = c1 ? t1 : (c2 ? t : t2);
      v1 = c1 ? v : v1;
      t1 = c1 ? t : t1;
    }
  }

  cand[((size_t)gi << 6) + lane] =
      (u16)((unsigned)t1 | ((unsigned)t2 << 5) | ((unsigned)t3 << 10));
  float bmax = b4;
  for (int o = 1; o < 64; o <<= 1)
    bmax = fmaxf(bmax, __shfl_xor(bmax, o, 64));
  if (lane == 0) bound[gi] = bmax;       // valid until next refresh

  int j1 = (t1 << 6) + lane;
  for (int o = 1; o < 64; o <<= 1) {
    float ov1 = __shfl_xor(v1, o, 64);
    float ov2 = __shfl_xor(v2, o, 64);
    int oj1 = __shfl_xor(j1, o, 64);
    bool ow = (ov1 > v1) || (ov1 == v1 && oj1 < j1);
    float loser = ow ? v1 : ov1;
    v1 = ow ? ov1 : v1;
    j1 = ow ? oj1 : j1;
    v2 = fmaxf(fmaxf(v2, ov2), loser);
  }
  post_bid(pb_write, bidt, b, gi, i, j1, v1, v2, eps, it, lane);
}

// Writer duty for the launched wide kernels (blk < 64 covers [0, BM)).
__device__ __forceinline__ void writer_duty(
    const float4* __restrict__ p2w_old, float4* __restrict__ p2w_new,
    const u64* __restrict__ pb_read, int blk, int tid, int it) {
  if (blk < 64) {
    int idx = blk * 256 + tid;
    float4 q = p2w_old[idx];
    if (it > 0) {
      u64 k = pb_read[idx];
      if ((int)(k >> 43) == it)
        q.w = q.w + __uint_as_float((unsigned)(k >> 11));  // reference add
    }
    p2w_new[idx] = q;
  }
}

// ---------- wide shape: 1 wave/point, 4096 blocks (its 0..LATE-1) ----------
__global__ __launch_bounds__(256) void iter_kernel(
    const float* __restrict__ xyz1,
    const float4* __restrict__ p2w_old, float4* __restrict__ p2w_new,
    const float* __restrict__ epsp,
    const u64* __restrict__ pb_read, u64* __restrict__ pb_write,
    const int* __restrict__ assign_old, int* __restrict__ assign_new,
    int* __restrict__ bidt, u16* __restrict__ cand,
    float* __restrict__ bound, int it) {
#pragma clang fp contract(off)
  const int blk = blockIdx.x;            // [0, 4096)
  const int b = blk & 7;
  const int wave = threadIdx.x >> 6;
  const int lane = threadIdx.x & 63;
  const int i = ((blk >> 3) << 2) + wave;
  const int gi = b * NN + i;
  const u64* keys = pb_read + b * MM;
  const float4* pold = p2w_old + b * MM;

  writer_duty(p2w_old, p2w_new, pb_read, blk, threadIdx.x, it);

  bool need_bid;
  int cur = -1;
  if (it == 0) {
    need_bid = true;
  } else {
    int a_old = assign_old[gi];
    if (a_old >= 0) {
      u64 k = keys[a_old];
      if ((int)(k >> 43) == it) need_bid = true;
      else { need_bid = false; cur = a_old; }
    } else {
      int jt = bidt[gi];
      u64 k = keys[jt];
      if ((2047 - (int)(k & 0x7FF)) == i) { need_bid = false; cur = jt; }
      else need_bid = true;
    }
  }
  if (lane == 0) assign_new[gi] = need_bid ? -1 : cur;
  if (!need_bid) return;

  const float eps = *epsp;
  const float* x1p = xyz1 + (size_t)gi * 3;
  const float x1 = x1p[0], y1 = x1p[1], z1 = x1p[2];

  if (it > 0 && try_cert(pold, keys, cand, bound, pb_write, bidt,
                         x1, y1, z1, b, gi, i, it, eps, lane))
    return;
  scan_bid(pold, keys, cand, bound, pb_write, bidt,
           x1, y1, z1, b, gi, i, it, eps, lane);
}

// ---------- late phase: ONE WORKGROUP PER BATCH, its [LATE,ITERS)+final ---
// 8 blocks x 1024 threads (16 waves). Batch state is block-private =>
// __syncthreads is the only sync needed. Per iteration:
//   reset nact | fold(strided)        (fold writes p2w_new; nothing reads it
//   __syncthreads()                    this iteration - one-behind fold)
//   status(strided): assign_new, compact actives into LDS act[]
//   __syncthreads()
//   1 wave per active point: try_cert / scan_bid (unchanged math)
//   __threadfence()                   (CU-shared L1 invalidate: plain reads
//   __syncthreads()                    next iter see this iter's atomicMax)
__global__ __launch_bounds__(1024) void auction_late_batch(
    const float* __restrict__ xyz1, const float* __restrict__ epsp,
    float4* __restrict__ p2w, u64* __restrict__ pbuf,
    int* __restrict__ assign, int* __restrict__ bidt,
    u16* __restrict__ cand, float* __restrict__ bound,
    float* __restrict__ out) {
#pragma clang fp contract(off)
  const int b = blockIdx.x;              // [0, 8): one batch per block
  const int wave = threadIdx.x >> 6;     // [0, 16)
  const int lane = threadIdx.x & 63;
  __shared__ int act[NN];
  __shared__ int nact;
  const float eps = *epsp;

  for (int it = LATE; it < ITERS; ++it) {
    const float4* p2w_old = p2w + (size_t)(it & 1) * BM;
    float4* p2w_new = p2w + (size_t)((it + 1) & 1) * BM;
    const u64* pb_read = pbuf + (size_t)((it + 1) & 1) * BM;
    u64* pb_write = pbuf + (size_t)(it & 1) * BM;
    const int* assign_old = assign + (size_t)(it & 1) * BN;
    int* assign_new = assign + (size_t)((it + 1) & 1) * BN;
    const u64* keys = pb_read + b * MM;
    const float4* pold = p2w_old + b * MM;

    if (threadIdx.x == 0) nact = 0;
    // price fold for this batch (bit-identical to writer_duty, it>0 here)
    for (int j = threadIdx.x; j < MM; j += 1024) {
      int idx = b * MM + j;
      float4 q = p2w_old[idx];
      u64 kk = pb_read[idx];
      if ((int)(kk >> 43) == it)
        q.w = q.w + __uint_as_float((unsigned)(kk >> 11)); // reference add
      p2w_new[idx] = q;
    }
    __syncthreads();                     // nact reset visible

    // status + active compaction (same decision logic as before)
    for (int i = threadIdx.x; i < NN; i += 1024) {
      const int gi = b * NN + i;
      int cur = -1, need = 0;
      int a_old = assign_old[gi];
      if (a_old >= 0) {
        u64 kk = keys[a_old];
        if ((int)(kk >> 43) == it) need = 1;
        else cur = a_old;
      } else {
        int jt = bidt[gi];
        u64 kk = keys[jt];
        if ((2047 - (int)(kk & 0x7FF)) == i) cur = jt;
        else need = 1;
      }
      assign_new[gi] = need ? -1 : cur;
      if (need) {
        int pos = atomicAdd(&nact, 1);   // LDS atomic; order-free
        act[pos] = i;
      }
    }
    __syncthreads();                     // act[], nact complete

    // 1 wave per active point (wide shape, zero launch/barrier overhead)
    const int na = nact;
    for (int a = wave; a < na; a += 16) {
      const int i = act[a];
      const int gi = b * NN + i;
      const float* x1p = xyz1 + (size_t)gi * 3;
      const float x1 = x1p[0], y1 = x1p[1], z1 = x1p[2];
      if (try_cert(pold, keys, cand, bound, pb_write, bidt,
                   x1, y1, z1, b, gi, i, it, eps, lane))
        continue;
      scan_bid(pold, keys, cand, bound, pb_write, bidt,
               x1, y1, z1, b, gi, i, it, eps, lane);
    }
    __threadfence();                     // L1 inv: atomicMax results visible
    __syncthreads();                     // all writes of this iter done
  }

  // ---- final: resolve tag-ITERS bids, emit dist + assign ----------------
  // After it=ITERS-1: pb_last = pbuf[1] (tag 20 bids), assign_old=assign[0].
  const u64* fkeys = pbuf + (size_t)BM + (size_t)b * MM;
  for (int i = threadIdx.x; i < NN; i += 1024) {
    int idx = b * NN + i;
    int a_old = assign[idx];
    int cur;
    if (a_old >= 0) {
      u64 kk = fkeys[a_old];
      cur = ((int)(kk >> 43) == ITERS) ? -1 : a_old;  // evicted at the end?
    } else {
      int jt = bidt[idx];
      u64 kk = fkeys[jt];
      cur = ((2047 - (int)(kk & 0x7FF)) == i) ? jt : -1;
    }

    float d = 0.f;
    if (cur >= 0) {
      float4 q = p2w[b * MM + cur];      // coords identical in both buffers
      float dx = xyz1[idx * 3 + 0] - q.x;
      float dy = xyz1[idx * 3 + 1] - q.y;
      float dz = xyz1[idx * 3 + 2] - q.z;
      d = dx * dx;
      d = d + dy * dy;
      d = d + dz * dz;
    }
    out[idx] = d;
    out[BN + idx] = (float)cur;          // assignment as float32 values
  }
}

extern "C" void kernel_launch(void* const* d_in, const int* in_sizes, int n_in,
                              void* d_out, int out_size, void* d_ws, size_t ws_size,
                              hipStream_t stream) {
  const float* xyz1 = (const float*)d_in[0];
  const float* xyz2 = (const float*)d_in[1];
  const float* eps  = (const float*)d_in[2];
  // d_in[3] = iters (fixed at 20 by setup_inputs); hard-coded for capture.
  float* out = (float*)d_out;

  char* ws = (char*)d_ws;
  float4* p2w = (float4*)ws;                       // [2][BM]
  u64* pbuf = (u64*)(ws + 524288);                 // [2][BM]
  int* assign = (int*)(ws + 786432);               // [2][BN]
  int* bidt = (int*)(ws + 917504);                 // [BN]
  float* bound = (float*)(ws + 983040);            // [BN]
  u16* cand = (u16*)(ws + 1048576);                // [BN*64]

  pack_kernel<<<BM / 256, 256, 0, stream>>>(xyz2, p2w, pbuf);

  for (int it = 0; it < LATE; ++it) {
    const float4* po = p2w + (size_t)(it & 1) * BM;
    float4* pn = p2w + (size_t)((it + 1) & 1) * BM;
    const u64* pr = pbuf + (size_t)((it + 1) & 1) * BM;
    u64* pw = pbuf + (size_t)(it & 1) * BM;
    const int* ao = assign + (size_t)(it & 1) * BN;
    int* an = assign + (size_t)((it + 1) & 1) * BN;
    iter_kernel<<<4096, 256, 0, stream>>>(xyz1, po, pn, eps, pr, pw, ao,
                                          an, bidt, cand, bound, it);
  }

  // its [LATE, 20) + final: one workgroup per batch, intra-block sync only
  auction_late_batch<<<BB, 1024, 0, stream>>>(
      xyz1, eps, p2w, pbuf, assign, bidt, cand, bound, out);
}

// Round 5
// 236.802 us; speedup vs baseline: 3.3699x; 3.3699x over previous
//
#include <hip/hip_runtime.h>
#include <cstdint>

// Problem constants (fixed by setup_inputs): B=8, n=m=2048, iters=20.
#define BB 8
#define NN 2048
#define MM 2048
#define ITERS 20
#define BM (BB * MM)
#define BN (BB * NN)
#define LATE 6    // its [0,LATE) wide tiled kernel; rest r0's launched compact

typedef unsigned long long u64;
typedef unsigned short u16;

// r0 machine (223 us, absmax 0) with the WIDE PHASE rebuilt (r5):
//  - r1-r4 lessons: any in-kernel cross-block sync costs ~30us/round fixed;
//    8-block fusion starves the GPU (r4: 702us @ 1.4% occupancy). Late
//    phase compute is only ~2us/iter -> r0's launched late structure is
//    near-optimal. The fat is the wide phase: ~23us/iter, L2-BW-bound
//    (16384 waves x 48KB re-read = 786MB @ 34.5TB/s).
//  - r5 wide phase: (a) PRE-FOLD prices into p2w[(it+1)&1] via a tiny
//    fold_kernel before wide its 1..5 (same q.w+incr add, once per object
//    instead of per reader -> bit-identical; scans no longer read keys);
//    (b) 4 points/wave, 32KB LDS-staged table, interleaved scan: one
//    ds_read_b128 stream feeds 4 top-3 trackers -> L2 bytes/iter 786MB ->
//    ~35MB, LDS 134MB @ 69TB/s. Blocks with no scanner skip staging.
//  - late its [6,20) + final: VERBATIM r0 launched kernels.
//
// Workspace (bytes):
//   p2w    float4[2][BM]  xyz2 + price in .w   off 0        524288
//   pbuf   u64[2][BM]     tagged bid keys      off 524288   262144
//   assign int[2][BN]     point -> object      off 786432   131072
//   bidt   int[BN]        last bid target      off 917504    65536
//   bound  f32[BN]        cert bounds          off 983040    65536
//   cand   u16[BN*64]     t1|t2<<5|t3<<10      off 1048576 2097152
// total 3145728 (< proven-available 8978432).
//
// Bid key: (tag << 43) | (float_bits(incr) << 11) | (2047 - i)
//   tag = it+1 (0 = empty); fresh tags dominate stale under atomicMax so
//   pbuf is never reset. incr > 0 => float bit order == value order;
//   (2047-i) = min-index tie-break (reference min-winner semantics).
// Price invariant: before iteration it, p2w[it&1] = prices folded through
//   tag it-1. fold_kernel at it: reads p2w[it&1] + tag-it keys ->
//   writes p2w[(it+1)&1] folded through tag it (= effective prices for
//   iteration it). Wide scans read p2w[(it+1)&1] only. it0 reads p2w[1]
//   (raw copy, prices 0; pack writes both halves). Late its keep the r0
//   one-behind fold + on-the-fly key add (same invariant).

__global__ __launch_bounds__(256) void pack_kernel(
    const float* __restrict__ xyz2, float4* __restrict__ p2w,
    u64* __restrict__ pbuf) {
  int idx = blockIdx.x * 256 + threadIdx.x;  // [0, BM)
  float4 q = make_float4(xyz2[idx * 3], xyz2[idx * 3 + 1],
                         xyz2[idx * 3 + 2], 0.f);
  p2w[idx] = q;
  p2w[BM + idx] = q;                   // both halves raw (it0 reads [1])
  pbuf[idx] = 0ULL;
  pbuf[BM + idx] = 0ULL;
}

// Pre-fold: p2w_new = p2w_old with tag-it increments applied. Exactly the
// writer_duty add (one float add, same operands) done once per object.
__global__ __launch_bounds__(256) void fold_kernel(
    const float4* __restrict__ p2w_old, float4* __restrict__ p2w_new,
    const u64* __restrict__ pb_read, int it) {
#pragma clang fp contract(off)
  int idx = blockIdx.x * 256 + threadIdx.x;  // [0, BM)
  float4 q = p2w_old[idx];
  u64 k = pb_read[idx];
  if ((int)(k >> 43) == it)
    q.w = q.w + __uint_as_float((unsigned)(k >> 11));    // reference add
  p2w_new[idx] = q;
}

// ---------- shared device helpers (inlined) ----------
__device__ __forceinline__ void post_bid(u64* __restrict__ pb_write,
                                         int* __restrict__ bidt,
                                         int b, int gi, int i, int j1,
                                         float v1, float v2, float eps,
                                         int it, int lane) {
  if (lane == 0) {
    float incr = (v1 - v2) + eps;        // top1 - top2 + eps
    u64 key = ((u64)(unsigned)(it + 1) << 43) |
              ((u64)__float_as_uint(incr) << 11) |
              (u64)(unsigned)(2047 - i);
    atomicMax(&pb_write[b * MM + j1], key);
    bidt[gi] = j1;
  }
}

// ---- late-phase (r0) evaluators: on-the-fly key fold ----
__device__ __forceinline__ float eval_cand(
    const float4* __restrict__ pold, const u64* __restrict__ keys,
    float x1, float y1, float z1, int j, int it) {
  float4 q = pold[j];
  u64 k = keys[j];
  float pr = q.w;
  if ((int)(k >> 43) == it)
    pr = pr + __uint_as_float((unsigned)(k >> 11));      // reference add
  float dx = x1 - q.x, dy = y1 - q.y, dz = z1 - q.z;
  float c = dx * dx;
  c = c + dy * dy;                       // contract(off): matches numpy
  c = c + dz * dz;
  return -c - pr;                        // -cost - price, reference order
}

// ---- wide-phase evaluator: pre-folded prices, no keys ----
__device__ __forceinline__ float eval_pf(
    const float4* __restrict__ pfb, float x1, float y1, float z1, int j) {
  float4 q = pfb[j];
  float dx = x1 - q.x, dy = y1 - q.y, dz = z1 - q.z;
  float c = dx * dx;
  c = c + dy * dy;
  c = c + dz * dz;
  return -c - q.w;                       // q.w already folded (same add)
}

// Shared cert merge/reduce body (exact value,min-index ordering).
#define CERT_BODY(EVA, EVB, EVC)                                          \
  float va = (EVA), vb = (EVB), vc = (EVC);                               \
  bool oab = (vb > va) || (vb == va && jb < ja);                          \
  float h1 = oab ? vb : va;  int hj = oab ? jb : ja;                      \
  float l1 = oab ? va : vb;  int lj = oab ? ja : jb;                      \
  bool oc1 = (vc > h1) || (vc == h1 && jc < hj);                          \
  bool oc2 = (vc > l1) || (vc == l1 && jc < lj);                          \
  float v1 = oc1 ? vc : h1;                                               \
  int j1 = oc1 ? jc : hj;                                                 \
  float v2 = oc1 ? h1 : (oc2 ? vc : l1);                                  \
  for (int o = 1; o < 64; o <<= 1) {                                      \
    float ov1 = __shfl_xor(v1, o, 64);                                    \
    float ov2 = __shfl_xor(v2, o, 64);                                    \
    int oj1 = __shfl_xor(j1, o, 64);                                      \
    bool w2 = (ov1 > v1) || (ov1 == v1 && oj1 < j1);                      \
    float loser = w2 ? v1 : ov1;                                          \
    v1 = w2 ? ov1 : v1;                                                   \
    j1 = w2 ? oj1 : j1;                                                   \
    v2 = fmaxf(fmaxf(v2, ov2), loser);                                    \
  }

// Cert for late phase (r0 exact).
__device__ __forceinline__ bool try_cert(
    const float4* __restrict__ pold, const u64* __restrict__ keys,
    const u16* __restrict__ cand, const float* __restrict__ bound,
    u64* __restrict__ pb_write, int* __restrict__ bidt,
    float x1, float y1, float z1, int b, int gi, int i, int it,
    float eps, int lane) {
  const float bnd = bound[gi];
  const unsigned cw = cand[((size_t)gi << 6) + lane];
  const int ja = (((int)cw & 31) << 6) + lane;
  const int jb = ((((int)cw >> 5) & 31) << 6) + lane;
  const int jc = ((((int)cw >> 10) & 31) << 6) + lane;
  CERT_BODY(eval_cand(pold, keys, x1, y1, z1, ja, it),
            eval_cand(pold, keys, x1, y1, z1, jb, it),
            eval_cand(pold, keys, x1, y1, z1, jc, it))
  if (v2 > bnd) {
    post_bid(pb_write, bidt, b, gi, i, j1, v1, v2, eps, it, lane);
    return true;
  }
  return false;
}

// Cert for wide phase (pre-folded table, no keys).
__device__ __forceinline__ bool try_cert_pf(
    const float4* __restrict__ pfb,
    const u16* __restrict__ cand, const float* __restrict__ bound,
    u64* __restrict__ pb_write, int* __restrict__ bidt,
    float x1, float y1, float z1, int b, int gi, int i, int it,
    float eps, int lane) {
  const float bnd = bound[gi];
  const unsigned cw = cand[((size_t)gi << 6) + lane];
  const int ja = (((int)cw & 31) << 6) + lane;
  const int jb = ((((int)cw >> 5) & 31) << 6) + lane;
  const int jc = ((((int)cw >> 10) & 31) << 6) + lane;
  CERT_BODY(eval_pf(pfb, x1, y1, z1, ja),
            eval_pf(pfb, x1, y1, z1, jb),
            eval_pf(pfb, x1, y1, z1, jc))
  if (v2 > bnd) {
    post_bid(pb_write, bidt, b, gi, i, j1, v1, v2, eps, it, lane);
    return true;
  }
  return false;
}

// Tail of a scan: cand refresh, bound reduce+store, top-1/2 butterfly, bid.
// Exactly scan_bid's tail (r0).
__device__ __forceinline__ void scan_tail(
    u16* __restrict__ cand, float* __restrict__ bound,
    u64* __restrict__ pb_write, int* __restrict__ bidt,
    float v1, float v2, float b4, int t1, int t2, int t3,
    int b, int gi, int i, int it, float eps, int lane) {
  cand[((size_t)gi << 6) + lane] =
      (u16)((unsigned)t1 | ((unsigned)t2 << 5) | ((unsigned)t3 << 10));
  float bmax = b4;
  for (int o = 1; o < 64; o <<= 1)
    bmax = fmaxf(bmax, __shfl_xor(bmax, o, 64));
  if (lane == 0) bound[gi] = bmax;       // valid until next refresh

  int j1 = (t1 << 6) + lane;
  for (int o = 1; o < 64; o <<= 1) {
    float ov1 = __shfl_xor(v1, o, 64);
    float ov2 = __shfl_xor(v2, o, 64);
    int oj1 = __shfl_xor(j1, o, 64);
    bool ow = (ov1 > v1) || (ov1 == v1 && oj1 < j1);
    float loser = ow ? v1 : ov1;
    v1 = ow ? ov1 : v1;
    j1 = ow ? oj1 : j1;
    v2 = fmaxf(fmaxf(v2, ov2), loser);
  }
  post_bid(pb_write, bidt, b, gi, i, j1, v1, v2, eps, it, lane);
}

// Full scan for late phase (r0 exact: on-the-fly fold, 1 point/wave call).
__device__ __forceinline__ void scan_bid(
    const float4* __restrict__ pold, const u64* __restrict__ keys,
    u16* __restrict__ cand, float* __restrict__ bound,
    u64* __restrict__ pb_write, int* __restrict__ bidt,
    float x1, float y1, float z1, int b, int gi, int i, int it,
    float eps, int lane) {
  const float NEG_INF = __int_as_float(0xff800000);
  float v1 = NEG_INF, v2 = NEG_INF, v3 = NEG_INF, b4 = NEG_INF;
  int t1 = 0, t2 = 0, t3 = 0;
#pragma unroll 4
  for (int t = 0; t < MM / 64; ++t) {
    int j = (t << 6) + lane;
    float4 q = pold[j];
    float pr = q.w;
    u64 k = keys[j];
    if ((int)(k >> 43) == it)
      pr = pr + __uint_as_float((unsigned)(k >> 11));     // reference add
    float dx = x1 - q.x;
    float dy = y1 - q.y;
    float dz = z1 - q.z;
    float c = dx * dx;
    c = c + dy * dy;                     // contract(off): matches numpy
    c = c + dz * dz;
    float v = -c - pr;
    bool c1 = v > v1;
    bool c2 = v > v2;
    bool c3 = v > v3;
    b4 = fmaxf(b4, (c1 | c2 | c3) ? v3 : v);
    v3 = (c1 | c2) ? v2 : (c3 ? v : v3);
    t3 = (c1 | c2) ? t2 : (c3 ? t : t3);
    v2 = c1 ? v1 : (c2 ? v : v2);
    t2 = c1 ? t1 : (c2 ? t : t2);
    v1 = c1 ? v : v1;
    t1 = c1 ? t : t1;
  }
  scan_tail(cand, bound, pb_write, bidt, v1, v2, b4, t1, t2, t3,
            b, gi, i, it, eps, lane);
}

// Writer duty (late launched kernels; blk < 64 covers [0, BM)).
__device__ __forceinline__ void writer_duty(
    const float4* __restrict__ p2w_old, float4* __restrict__ p2w_new,
    const u64* __restrict__ pb_read, int blk, int tid, int it) {
  if (blk < 64) {
    int idx = blk * 256 + tid;
    float4 q = p2w_old[idx];
    if (it > 0) {
      u64 k = pb_read[idx];
      if ((int)(k >> 43) == it)
        q.w = q.w + __uint_as_float((unsigned)(k >> 11));  // reference add
    }
    p2w_new[idx] = q;
  }
}

// ---------- wide phase: tiled LDS scan, its [0, LATE) --------------------
// 1024 blocks x 256 thr (4 waves x 4 points). pf = pre-folded prices for
// this iteration. Per block: status/cert first (global reads), then if any
// wave still needs a full scan, stage the batch's 32KB table into LDS once
// and run a 4-slot interleaved scan (one ds_read_b128 feeds 4 trackers).
__global__ __launch_bounds__(256) void wide_kernel(
    const float* __restrict__ xyz1, const float4* __restrict__ pf,
    const float* __restrict__ epsp,
    const u64* __restrict__ pb_read, u64* __restrict__ pb_write,
    const int* __restrict__ assign_old, int* __restrict__ assign_new,
    int* __restrict__ bidt, u16* __restrict__ cand,
    float* __restrict__ bound, int it) {
#pragma clang fp contract(off)
  const int blk = blockIdx.x;            // [0, 1024)
  const int b = blk & 7;
  const int k = blk >> 3;                // [0, 128)
  const int wave = threadIdx.x >> 6;
  const int lane = threadIdx.x & 63;
  const int base = (k << 4) + (wave << 2);   // 4 points per wave
  const u64* keys = pb_read + b * MM;
  const float4* pfb = pf + b * MM;
  __shared__ float4 sP[MM];              // 32 KB staged table
  __shared__ int sFlag;
  const float eps = *epsp;

  // status (it==0: everyone bids; else r0 logic), lane-parallel
  int need = 0;
  if (lane < 4) {
    const int i = base + lane;
    const int gi = b * NN + i;
    if (it == 0) {
      need = 1;
      assign_new[gi] = -1;
    } else {
      int cur = -1;
      int a_old = assign_old[gi];
      if (a_old >= 0) {
        u64 kk = keys[a_old];
        if ((int)(kk >> 43) == it) need = 1;
        else cur = a_old;
      } else {
        int jt = bidt[gi];
        u64 kk = keys[jt];
        if ((2047 - (int)(kk & 0x7FF)) == i) cur = jt;
        else need = 1;
      }
      assign_new[gi] = need ? -1 : cur;
    }
  }
  unsigned sm = (unsigned)(__ballot(need) & 0xFULL);

  // cert pass (global pre-folded reads; no staging needed)
  if (it > 0 && sm) {
    for (int p = 0; p < 4; ++p) {
      if (!((sm >> p) & 1)) continue;    // wave-uniform
      const int i = base + p;
      const int gi = b * NN + i;
      const float* xp = xyz1 + (size_t)gi * 3;
      if (try_cert_pf(pfb, cand, bound, pb_write, bidt,
                      xp[0], xp[1], xp[2], b, gi, i, it, eps, lane))
        sm &= ~(1u << p);
    }
  }

  // block-level stage decision
  if (threadIdx.x == 0) sFlag = 0;
  __syncthreads();
  if (sm && lane == 0) sFlag = 1;        // benign same-value race
  __syncthreads();
  if (sFlag) {
    for (int j = threadIdx.x; j < MM; j += 256) sP[j] = pfb[j];
    __syncthreads();
    if (sm) {
      // 4-slot interleaved scan from LDS (per-slot op order == r0 scan)
      const float NEG_INF = __int_as_float(0xff800000);
      float v1[4], v2[4], v3[4], b4[4], xs[4], ys[4], zs[4];
      int t1[4], t2[4], t3[4];
#pragma unroll
      for (int p = 0; p < 4; ++p) {
        v1[p] = v2[p] = v3[p] = b4[p] = NEG_INF;
        t1[p] = t2[p] = t3[p] = 0;
        const float* xp = xyz1 + (size_t)(b * NN + base + p) * 3;
        xs[p] = xp[0]; ys[p] = xp[1]; zs[p] = xp[2];
      }
#pragma unroll 2
      for (int t = 0; t < MM / 64; ++t) {
        float4 q = sP[(t << 6) + lane];
#pragma unroll
        for (int p = 0; p < 4; ++p) {
          float dx = xs[p] - q.x;
          float dy = ys[p] - q.y;
          float dz = zs[p] - q.z;
          float c = dx * dx;
          c = c + dy * dy;
          c = c + dz * dz;
          float v = -c - q.w;            // pre-folded price
          bool c1 = v > v1[p];
          bool c2 = v > v2[p];
          bool c3 = v > v3[p];
          b4[p] = fmaxf(b4[p], (c1 | c2 | c3) ? v3[p] : v);
          v3[p] = (c1 | c2) ? v2[p] : (c3 ? v : v3[p]);
          t3[p] = (c1 | c2) ? t2[p] : (c3 ? t : t3[p]);
          v2[p] = c1 ? v1[p] : (c2 ? v : v2[p]);
          t2[p] = c1 ? t1[p] : (c2 ? t : t2[p]);
          v1[p] = c1 ? v : v1[p];
          t1[p] = c1 ? t : t1[p];
        }
      }
#pragma unroll
      for (int p = 0; p < 4; ++p) {
        if (!((sm >> p) & 1)) continue;  // wave-uniform
        const int i = base + p;
        scan_tail(cand, bound, pb_write, bidt,
                  v1[p], v2[p], b4[p], t1[p], t2[p], t3[p],
                  b, b * NN + i, i, it, eps, lane);
      }
    }
  }
}

// ---------- compact shape: 4 points/wave, 1024 blocks (its >= LATE) ------
// VERBATIM r0 iter_late_kernel.
__global__ __launch_bounds__(256) void iter_late_kernel(
    const float* __restrict__ xyz1,
    const float4* __restrict__ p2w_old, float4* __restrict__ p2w_new,
    const float* __restrict__ epsp,
    const u64* __restrict__ pb_read, u64* __restrict__ pb_write,
    const int* __restrict__ assign_old, int* __restrict__ assign_new,
    int* __restrict__ bidt, u16* __restrict__ cand,
    float* __restrict__ bound, int it) {
#pragma clang fp contract(off)
  const int blk = blockIdx.x;            // [0, 1024)
  const int b = blk & 7;
  const int wave = threadIdx.x >> 6;
  const int lane = threadIdx.x & 63;
  const int base = ((blk >> 3) << 4) + (wave << 2);   // 4 points per wave
  const u64* keys = pb_read + b * MM;
  const float4* pold = p2w_old + b * MM;

  writer_duty(p2w_old, p2w_new, pb_read, blk, threadIdx.x, it);

  // lane-parallel status (it >= LATE > 0 always here)
  int need = 0;
  if (lane < 4) {
    const int i = base + lane;
    const int gi = b * NN + i;
    int cur = -1;
    int a_old = assign_old[gi];
    if (a_old >= 0) {
      u64 k = keys[a_old];
      if ((int)(k >> 43) == it) need = 1;
      else cur = a_old;
    } else {
      int jt = bidt[gi];
      u64 k = keys[jt];
      if ((2047 - (int)(k & 0x7FF)) == i) cur = jt;
      else need = 1;
    }
    assign_new[gi] = need ? -1 : cur;
  }
  u64 m = __ballot(need);
  if ((m & 0xFULL) == 0) return;         // wave-uniform exit

  const float eps = *epsp;
  for (int p = 0; p < 4; ++p) {
    if (!((m >> p) & 1)) continue;       // wave-uniform branch
    const int i = base + p;
    const int gi = b * NN + i;
    const float* x1p = xyz1 + (size_t)gi * 3;
    const float x1 = x1p[0], y1 = x1p[1], z1 = x1p[2];
    if (try_cert(pold, keys, cand, bound, pb_write, bidt,
                 x1, y1, z1, b, gi, i, it, eps, lane))
      continue;
    scan_bid(pold, keys, cand, bound, pb_write, bidt,
             x1, y1, z1, b, gi, i, it, eps, lane);
  }
}

// Final: resolve tag-ITERS bids per point, emit dist + assign. (r0 exact)
__global__ __launch_bounds__(256) void final_kernel(
    const float* __restrict__ xyz1, const float4* __restrict__ p2f4,
    const u64* __restrict__ pb_last, const int* __restrict__ assign_old,
    const int* __restrict__ bidt, float* __restrict__ out) {
#pragma clang fp contract(off)
  int idx = blockIdx.x * 256 + threadIdx.x;  // [0, BN)
  int b = idx >> 11, i = idx & (NN - 1);
  const u64* keys = pb_last + b * MM;

  int a_old = assign_old[idx];
  int cur;
  if (a_old >= 0) {
    u64 k = keys[a_old];
    cur = ((int)(k >> 43) == ITERS) ? -1 : a_old;   // evicted at the end?
  } else {
    int jt = bidt[idx];
    u64 k = keys[jt];
    cur = ((2047 - (int)(k & 0x7FF)) == i) ? jt : -1;
  }

  float d = 0.f;
  if (cur >= 0) {
    float4 q = p2f4[b * MM + cur];       // coords identical in both buffers
    float dx = xyz1[idx * 3 + 0] - q.x;
    float dy = xyz1[idx * 3 + 1] - q.y;
    float dz = xyz1[idx * 3 + 2] - q.z;
    d = dx * dx;
    d = d + dy * dy;
    d = d + dz * dz;
  }
  out[idx] = d;
  out[BN + idx] = (float)cur;            // assignment as float32 values
}

extern "C" void kernel_launch(void* const* d_in, const int* in_sizes, int n_in,
                              void* d_out, int out_size, void* d_ws, size_t ws_size,
                              hipStream_t stream) {
  const float* xyz1 = (const float*)d_in[0];
  const float* xyz2 = (const float*)d_in[1];
  const float* eps  = (const float*)d_in[2];
  // d_in[3] = iters (fixed at 20 by setup_inputs); hard-coded for capture.
  float* out = (float*)d_out;

  char* ws = (char*)d_ws;
  float4* p2w = (float4*)ws;                       // [2][BM]
  u64* pbuf = (u64*)(ws + 524288);                 // [2][BM]
  int* assign = (int*)(ws + 786432);               // [2][BN]
  int* bidt = (int*)(ws + 917504);                 // [BN]
  float* bound = (float*)(ws + 983040);            // [BN]
  u16* cand = (u16*)(ws + 1048576);                // [BN*64]

  pack_kernel<<<BM / 256, 256, 0, stream>>>(xyz2, p2w, pbuf);

  for (int it = 0; it < LATE; ++it) {
    float4* pfit = p2w + (size_t)((it + 1) & 1) * BM;   // effective prices
    const u64* pr = pbuf + (size_t)((it + 1) & 1) * BM;
    u64* pw = pbuf + (size_t)(it & 1) * BM;
    const int* ao = assign + (size_t)(it & 1) * BN;
    int* an = assign + (size_t)((it + 1) & 1) * BN;
    if (it > 0)
      fold_kernel<<<BM / 256, 256, 0, stream>>>(
          p2w + (size_t)(it & 1) * BM, pfit, pr, it);
    wide_kernel<<<1024, 256, 0, stream>>>(xyz1, pfit, eps, pr, pw, ao, an,
                                          bidt, cand, bound, it);
  }

  for (int it = LATE; it < ITERS; ++it) {
    const float4* po = p2w + (size_t)(it & 1) * BM;
    float4* pn = p2w + (size_t)((it + 1) & 1) * BM;
    const u64* pr = pbuf + (size_t)((it + 1) & 1) * BM;
    u64* pw = pbuf + (size_t)(it & 1) * BM;
    const int* ao = assign + (size_t)(it & 1) * BN;
    int* an = assign + (size_t)((it + 1) & 1) * BN;
    iter_late_kernel<<<1024, 256, 0, stream>>>(xyz1, po, pn, eps, pr, pw,
                                               ao, an, bidt, cand, bound,
                                               it);
  }

  // kernel 19 wrote pbuf[1] (tag 20) and assign_new = assign[0]
  final_kernel<<<BN / 256, 256, 0, stream>>>(
      xyz1, p2w, pbuf + (size_t)BM, assign, bidt, out);
}